// Round 1
// baseline (170.947 us; speedup 1.0000x reference)
//
#include <hip/hip_runtime.h>
#include <math.h>

#define D 256
#define NPROTO 1024
#define BN 32
#define BI 128
#define BK 32

// ---- hex-grid neighborhood H[i,j] computed on the fly (fp64, matches np ref) ----
__device__ __forceinline__ void proto_pos(int idx, double& x, double& y) {
    int r = idx >> 5, c = idx & 31;
    x = (double)c + 0.5 * (double)(r & 1);
    y = (double)r * 0.86602540378443864676;  // sqrt(3)/2
}

__device__ __forceinline__ float hval(int i, int j) {
    double xi, yi, xj, yj;
    proto_pos(i, xi, yi);
    proto_pos(j, xj, yj);
    double dx0 = xi - xj, dy0 = yi - yj;
    const double W = 32.0;
    const double Hh = 27.712812921102035;  // 32*sqrt(3)/2
    double best = 1e300;
#pragma unroll
    for (int sx = -1; sx <= 1; ++sx) {
        double dx = dx0 + (double)sx * W;
#pragma unroll
        for (int sy = -1; sy <= 1; ++sy) {
            double dy = dy0 + (double)sy * Hh;
            double d2 = dx * dx + dy * dy;
            best = fmin(best, d2);
        }
    }
    return (float)exp(-0.5 * best);
}

// ---- k0: p2[j] = ||P[j]||^2, one wave per row ----
__global__ void p2_kernel(const float* __restrict__ P, float* __restrict__ p2) {
    int j = blockIdx.x;
    int lane = threadIdx.x;  // 64
    float4 v = reinterpret_cast<const float4*>(P + j * D)[lane];
    float s = v.x * v.x + v.y * v.y + v.z * v.z + v.w * v.w;
#pragma unroll
    for (int off = 32; off >= 1; off >>= 1) s += __shfl_down(s, off);
    if (lane == 0) p2[j] = s;
}

// ---- k1: G = H@P, hsum = H·1, hp2 = H·p2. 4 H-rows per block, 512 threads. ----
__global__ void __launch_bounds__(512) gmat_kernel(
    const float* __restrict__ P, const float* __restrict__ p2,
    float* __restrict__ G, float* __restrict__ hsum, float* __restrict__ hp2) {
    __shared__ __align__(16) float hbuf[2][4][256];
    __shared__ __align__(16) float gbuf[4][2][256];
    __shared__ float sbuf[512];

    int tid = threadIdx.x;
    int half = tid >> 8;      // 0..1
    int d = tid & 255;        // column of P / G
    int i0 = blockIdx.x * 4;  // 4 H-rows per block

    float g[4] = {0.f, 0.f, 0.f, 0.f};
    float hs[4] = {0.f, 0.f, 0.f, 0.f};
    float hq[4] = {0.f, 0.f, 0.f, 0.f};

    for (int cc = 0; cc < 2; ++cc) {
        int jc = (half * 2 + cc) * 256;
        int j = jc + d;
        float pj = p2[j];
#pragma unroll
        for (int r = 0; r < 4; ++r) {
            float h = hval(i0 + r, j);
            hbuf[half][r][d] = h;
            hs[r] += h;
            hq[r] += h * pj;
        }
        __syncthreads();
#pragma unroll 8
        for (int jj = 0; jj < 256; ++jj) {
            float pv = P[(jc + jj) * D + d];
#pragma unroll
            for (int r = 0; r < 4; ++r) g[r] += hbuf[half][r][jj] * pv;
        }
        __syncthreads();
    }

#pragma unroll
    for (int r = 0; r < 4; ++r) gbuf[r][half][d] = g[r];
    __syncthreads();
    if (half == 0) {
#pragma unroll
        for (int r = 0; r < 4; ++r)
            G[(i0 + r) * D + d] = gbuf[r][0][d] + gbuf[r][1][d];
    }

    // reduce hs / hq across 512 threads
#pragma unroll
    for (int r = 0; r < 4; ++r) {
        __syncthreads();
        sbuf[tid] = hs[r];
        __syncthreads();
        for (int s = 256; s >= 1; s >>= 1) {
            if (tid < s) sbuf[tid] += sbuf[tid + s];
            __syncthreads();
        }
        if (tid == 0) hsum[i0 + r] = sbuf[0];
    }
#pragma unroll
    for (int r = 0; r < 4; ++r) {
        __syncthreads();
        sbuf[tid] = hq[r];
        __syncthreads();
        for (int s = 256; s >= 1; s >>= 1) {
            if (tid < s) sbuf[tid] += sbuf[tid + s];
            __syncthreads();
        }
        if (tid == 0) hp2[i0 + r] = sbuf[0];
    }
}

// ---- k2: fused e = hsum[i]*x2[n] - 2*X·G^T + hp2[i]; out[n] = 0.5*min_i e ----
__global__ void __launch_bounds__(256) som_kernel(
    const float* __restrict__ X, const float* __restrict__ G,
    const float* __restrict__ hsum, const float* __restrict__ hp2,
    float* __restrict__ out) {
    __shared__ __align__(16) float Xs[BK][BN + 4];   // [32][36] k-major
    __shared__ __align__(16) float Gs[BK][BI + 4];   // [32][132] k-major
    __shared__ float x2s[BN];
    __shared__ float red[32][BN + 1];

    int tid = threadIdx.x;
    int n0 = blockIdx.x * BN;
    int ti = tid & 31;   // i-dim, x4 -> 128
    int tn = tid >> 5;   // n-dim (0..7), x4 -> 32

    // ---- x2 for the 32 rows of this block ----
    {
        int n_l = tid >> 3;  // 0..31
        int seg = tid & 7;   // 0..7
        const float4* row = reinterpret_cast<const float4*>(X + (size_t)(n0 + n_l) * D);
        float s = 0.f;
#pragma unroll
        for (int p = 0; p < 8; ++p) {
            float4 v = row[seg + p * 8];
            s += v.x * v.x + v.y * v.y + v.z * v.z + v.w * v.w;
        }
#pragma unroll
        for (int off = 4; off >= 1; off >>= 1) s += __shfl_down(s, off, 8);
        if (seg == 0) x2s[n_l] = s;
    }
    __syncthreads();
    float x2r[4];
#pragma unroll
    for (int a = 0; a < 4; ++a) x2r[a] = x2s[tn * 4 + a];

    float rmin4[4] = {3.4e38f, 3.4e38f, 3.4e38f, 3.4e38f};

    int k_l = tid & 31;
    int r0 = tid >> 5;  // 0..7

    for (int it = 0; it < NPROTO / BI; ++it) {
        float acc[4][4] = {{0.f}};
        for (int kt = 0; kt < D / BK; ++kt) {
            __syncthreads();  // protect LDS from previous iteration's readers
#pragma unroll
            for (int p = 0; p < 4; ++p) {
                int n_l = r0 + p * 8;
                Xs[k_l][n_l] = X[(size_t)(n0 + n_l) * D + kt * BK + k_l];
            }
#pragma unroll
            for (int p = 0; p < 16; ++p) {
                int i_l = r0 + p * 8;
                Gs[k_l][i_l] = G[(it * BI + i_l) * D + kt * BK + k_l];
            }
            __syncthreads();
#pragma unroll
            for (int kk = 0; kk < BK; ++kk) {
                float4 xv4 = *reinterpret_cast<const float4*>(&Xs[kk][tn * 4]);
                float4 gv4 = *reinterpret_cast<const float4*>(&Gs[kk][ti * 4]);
                float xv[4] = {xv4.x, xv4.y, xv4.z, xv4.w};
                float gv[4] = {gv4.x, gv4.y, gv4.z, gv4.w};
#pragma unroll
                for (int a = 0; a < 4; ++a)
#pragma unroll
                    for (int b = 0; b < 4; ++b)
                        acc[a][b] = fmaf(xv[a], gv[b], acc[a][b]);
            }
        }
        // epilogue: e = hsum*x2 - 2*acc + hp2, fold into running min
#pragma unroll
        for (int b = 0; b < 4; ++b) {
            int i = it * BI + ti * 4 + b;
            float hs_b = hsum[i];
            float hq_b = hp2[i];
#pragma unroll
            for (int a = 0; a < 4; ++a) {
                float e = fmaf(hs_b, x2r[a], hq_b) - 2.0f * acc[a][b];
                rmin4[a] = fminf(rmin4[a], e);
            }
        }
    }

    // ---- cross-thread min over ti ----
#pragma unroll
    for (int a = 0; a < 4; ++a) red[ti][tn * 4 + a] = rmin4[a];
    __syncthreads();
    if (tid < BN) {
        float m = red[0][tid];
#pragma unroll
        for (int t = 1; t < 32; ++t) m = fminf(m, red[t][tid]);
        out[n0 + tid] = 0.5f * m;
    }
}

extern "C" void kernel_launch(void* const* d_in, const int* in_sizes, int n_in,
                              void* d_out, int out_size, void* d_ws, size_t ws_size,
                              hipStream_t stream) {
    const float* X = (const float*)d_in[0];  // [16384, 256]
    const float* P = (const float*)d_in[1];  // [1024, 256]
    float* out = (float*)d_out;              // [1, 16384]
    int N = in_sizes[0] / D;                 // 16384

    float* ws = (float*)d_ws;
    float* p2 = ws;            // 1024
    float* hsum = ws + 1024;   // 1024
    float* hp2 = ws + 2048;    // 1024
    float* G = ws + 4096;      // 1024*256

    p2_kernel<<<NPROTO, 64, 0, stream>>>(P, p2);
    gmat_kernel<<<NPROTO / 4, 512, 0, stream>>>(P, p2, G, hsum, hp2);
    som_kernel<<<N / BN, 256, 0, stream>>>(X, G, hsum, hp2, out);
}

// Round 2
// 64.022 us; speedup vs baseline: 2.6701x; 2.6701x over previous
//
#include <hip/hip_runtime.h>
#include <hip/hip_bf16.h>
#include <math.h>

#define D 256
#define NPROTO 1024
#define ISPLIT 4

typedef __attribute__((ext_vector_type(8))) short short8;
typedef __attribute__((ext_vector_type(4))) float f32x4;

__device__ __forceinline__ short f2bf(float f) {
    union { __hip_bfloat16 b; short s; } u;
    u.b = __float2bfloat16(f);
    return u.s;
}

__device__ __forceinline__ void gload_lds16(void* lds, const void* g) {
    __builtin_amdgcn_global_load_lds(
        (const __attribute__((address_space(1))) unsigned*)g,
        (__attribute__((address_space(3))) unsigned*)lds, 16, 0, 0);
}

// ---- hex-grid neighborhood H[i,j] on the fly (fp64, matches np ref) ----
__device__ __forceinline__ void proto_pos(int idx, double& x, double& y) {
    int r = idx >> 5, c = idx & 31;
    x = (double)c + 0.5 * (double)(r & 1);
    y = (double)r * 0.86602540378443864676;  // sqrt(3)/2
}

__device__ __forceinline__ float hval(int i, int j) {
    double xi, yi, xj, yj;
    proto_pos(i, xi, yi);
    proto_pos(j, xj, yj);
    double dx0 = xi - xj, dy0 = yi - yj;
    const double W = 32.0;
    const double Hh = 27.712812921102035;  // 32*sqrt(3)/2
    double best = 1e300;
#pragma unroll
    for (int sx = -1; sx <= 1; ++sx) {
        double dx = dx0 + (double)sx * W;
#pragma unroll
        for (int sy = -1; sy <= 1; ++sy) {
            double dy = dy0 + (double)sy * Hh;
            double d2 = dx * dx + dy * dy;
            best = fmin(best, d2);
        }
    }
    return (float)exp(-0.5 * best);
}

// ---- k0: p2[j] = ||P[j]||^2 ----
__global__ void p2_kernel(const float* __restrict__ P, float* __restrict__ p2) {
    int j = blockIdx.x;
    int lane = threadIdx.x;  // 64
    float4 v = reinterpret_cast<const float4*>(P + j * D)[lane];
    float s = v.x * v.x + v.y * v.y + v.z * v.z + v.w * v.w;
#pragma unroll
    for (int off = 32; off >= 1; off >>= 1) s += __shfl_down(s, off);
    if (lane == 0) p2[j] = s;
}

// ---- k1: Gb = bf16(H@P), hsum = H·1, hp2 = H·p2 ----
__global__ void __launch_bounds__(512) gmat_kernel(
    const float* __restrict__ P, const float* __restrict__ p2,
    short* __restrict__ Gb, float* __restrict__ hsum, float* __restrict__ hp2) {
    __shared__ __align__(16) float hbuf[2][4][256];
    __shared__ __align__(16) float gbuf[4][2][256];
    __shared__ float sbuf[512];

    int tid = threadIdx.x;
    int half = tid >> 8;
    int d = tid & 255;
    int i0 = blockIdx.x * 4;

    float g[4] = {0.f, 0.f, 0.f, 0.f};
    float hs[4] = {0.f, 0.f, 0.f, 0.f};
    float hq[4] = {0.f, 0.f, 0.f, 0.f};

    for (int cc = 0; cc < 2; ++cc) {
        int jc = (half * 2 + cc) * 256;
        int j = jc + d;
        float pj = p2[j];
#pragma unroll
        for (int r = 0; r < 4; ++r) {
            float h = hval(i0 + r, j);
            hbuf[half][r][d] = h;
            hs[r] += h;
            hq[r] += h * pj;
        }
        __syncthreads();
#pragma unroll 8
        for (int jj = 0; jj < 256; ++jj) {
            float pv = P[(jc + jj) * D + d];
#pragma unroll
            for (int r = 0; r < 4; ++r) g[r] += hbuf[half][r][jj] * pv;
        }
        __syncthreads();
    }

#pragma unroll
    for (int r = 0; r < 4; ++r) gbuf[r][half][d] = g[r];
    __syncthreads();
    if (half == 0) {
#pragma unroll
        for (int r = 0; r < 4; ++r)
            Gb[(size_t)(i0 + r) * D + d] = f2bf(gbuf[r][0][d] + gbuf[r][1][d]);
    }

#pragma unroll
    for (int r = 0; r < 4; ++r) {
        __syncthreads();
        sbuf[tid] = hs[r];
        __syncthreads();
        for (int s = 256; s >= 1; s >>= 1) {
            if (tid < s) sbuf[tid] += sbuf[tid + s];
            __syncthreads();
        }
        if (tid == 0) hsum[i0 + r] = sbuf[0];
    }
#pragma unroll
    for (int r = 0; r < 4; ++r) {
        __syncthreads();
        sbuf[tid] = hq[r];
        __syncthreads();
        for (int s = 256; s >= 1; s >>= 1) {
            if (tid < s) sbuf[tid] += sbuf[tid + s];
            __syncthreads();
        }
        if (tid == 0) hp2[i0 + r] = sbuf[0];
    }
}

// ---- init out to +inf (uint view of positive floats is order-preserving) ----
__global__ void init_kernel(unsigned* __restrict__ out) {
    out[blockIdx.x * 256 + threadIdx.x] = 0x7f800000u;  // +inf
}

// ---- k2: MFMA fused e = hsum*x2 - 2*X·G^T + hp2; atomicMin of 0.5*min ----
// block: 512 thr (8 waves 4x2), tile 256n x 256i, BK=64, dbuf LDS, XOR swizzle
__global__ void __launch_bounds__(512, 2) som2_kernel(
    const float* __restrict__ X, const short* __restrict__ Gb,
    const float* __restrict__ hsum, const float* __restrict__ hp2,
    unsigned* __restrict__ out) {
    __shared__ __align__(16) short Xs[2][256 * 64];  // 2 x 32KB bf16
    __shared__ __align__(16) short Gs[2][256 * 64];  // 2 x 32KB bf16
    __shared__ float x2s[256];
    __shared__ float red[2][256];

    const int tid = threadIdx.x;
    const int lane = tid & 63;
    const int wid = tid >> 6;
    const int wr = wid >> 1;       // 0..3 : n quadrant (64 rows each)
    const int wc = wid & 1;        // 0..1 : i half (128 cols each)
    const int lm = lane & 15;
    const int lq = lane >> 4;
    const int n0 = blockIdx.x * 256;
    const int ib = blockIdx.y * 256;

    // staging geometry (shared by X and G): per q in 0..3, thread t covers
    // LDS bytes [t*16 + q*8192, +16) => row r = (t>>3)+64q, col bytes (t&7)*16,
    // swizzled source col = col ^ ((r&7)<<4)
    const int srow = tid >> 3;                 // 0..63
    const int scol = ((tid & 7) * 16) ^ ((srow & 7) << 4);  // swizzled byte col

    f32x4 acc[4][8];
#pragma unroll
    for (int m = 0; m < 4; ++m)
#pragma unroll
        for (int ni = 0; ni < 8; ++ni) acc[m][ni] = (f32x4){0.f, 0.f, 0.f, 0.f};

    float sq[4] = {0.f, 0.f, 0.f, 0.f};

    auto stage_G = [&](int nb, int kt) {
#pragma unroll
        for (int q = 0; q < 4; ++q) {
            int r = srow + (q << 6);
            const char* src = (const char*)(Gb + (size_t)(ib + r) * D) + kt * 128 + scol;
            gload_lds16((char*)(&Gs[nb][0]) + tid * 16 + q * 8192, src);
        }
    };

    auto stage_X = [&](int nb, int kt) {
        float4 u[4], v[4];
#pragma unroll
        for (int q = 0; q < 4; ++q) {
            int r = srow + (q << 6);
            const float* src = X + (size_t)(n0 + r) * D + kt * 64 + (scol >> 1);
            u[q] = ((const float4*)src)[0];
            v[q] = ((const float4*)src)[1];
        }
#pragma unroll
        for (int q = 0; q < 4; ++q) {
            sq[q] += u[q].x * u[q].x + u[q].y * u[q].y + u[q].z * u[q].z + u[q].w * u[q].w +
                     v[q].x * v[q].x + v[q].y * v[q].y + v[q].z * v[q].z + v[q].w * v[q].w;
            short8 w;
            w[0] = f2bf(u[q].x); w[1] = f2bf(u[q].y); w[2] = f2bf(u[q].z); w[3] = f2bf(u[q].w);
            w[4] = f2bf(v[q].x); w[5] = f2bf(v[q].y); w[6] = f2bf(v[q].z); w[7] = f2bf(v[q].w);
            *(short8*)((char*)(&Xs[nb][0]) + tid * 16 + q * 8192) = w;
        }
    };

    auto compute = [&](int cur) {
        const char* xb = (const char*)(&Xs[cur][0]);
        const char* gbp = (const char*)(&Gs[cur][0]);
        const int rsw = (lm & 7) << 4;  // frag rows have r&7 == lm&7
#pragma unroll
        for (int kk = 0; kk < 2; ++kk) {
            const int oo = (kk * 64 + lq * 16) ^ rsw;
            short8 a[4];
#pragma unroll
            for (int m = 0; m < 4; ++m) {
                int r = (wr << 6) + (m << 4) + lm;
                a[m] = *(const short8*)(xb + r * 128 + oo);
            }
#pragma unroll
            for (int ni = 0; ni < 8; ++ni) {
                int r = (wc << 7) + (ni << 4) + lm;
                short8 b = *(const short8*)(gbp + r * 128 + oo);
#pragma unroll
                for (int m = 0; m < 4; ++m)
                    acc[m][ni] = __builtin_amdgcn_mfma_f32_16x16x32_bf16(a[m], b, acc[m][ni], 0, 0, 0);
            }
        }
    };

    stage_G(0, 0);
    stage_X(0, 0);
#pragma unroll
    for (int t = 0; t < 4; ++t) {
        __syncthreads();
        if (t < 3) {
            stage_G((t + 1) & 1, t + 1);
            stage_X((t + 1) & 1, t + 1);
        }
        compute(t & 1);
    }

    // ---- x2 per row (from fp32 values accumulated during staging) ----
#pragma unroll
    for (int q = 0; q < 4; ++q) {
        float s = sq[q];
        s += __shfl_xor(s, 1);
        s += __shfl_xor(s, 2);
        s += __shfl_xor(s, 4);
        if ((tid & 7) == 0) x2s[srow + (q << 6)] = s;
    }
    __syncthreads();

    float x2v[4][4];
#pragma unroll
    for (int m = 0; m < 4; ++m)
#pragma unroll
        for (int j = 0; j < 4; ++j)
            x2v[m][j] = x2s[(wr << 6) + (m << 4) + (lq << 2) + j];

    float rmin[4][4];
#pragma unroll
    for (int m = 0; m < 4; ++m)
#pragma unroll
        for (int j = 0; j < 4; ++j) rmin[m][j] = 3.4e38f;

#pragma unroll
    for (int ni = 0; ni < 8; ++ni) {
        int ig = ib + (wc << 7) + (ni << 4) + lm;
        float hs = hsum[ig];
        float hq = hp2[ig];
#pragma unroll
        for (int m = 0; m < 4; ++m)
#pragma unroll
            for (int j = 0; j < 4; ++j) {
                float e = fmaf(hs, x2v[m][j], hq) - 2.0f * acc[m][ni][j];
                rmin[m][j] = fminf(rmin[m][j], e);
            }
    }

    // min across the 16 lanes (lm) holding different i
#pragma unroll
    for (int m = 0; m < 4; ++m)
#pragma unroll
        for (int j = 0; j < 4; ++j) {
            float v = rmin[m][j];
            v = fminf(v, __shfl_xor(v, 1));
            v = fminf(v, __shfl_xor(v, 2));
            v = fminf(v, __shfl_xor(v, 4));
            v = fminf(v, __shfl_xor(v, 8));
            rmin[m][j] = v;
        }
    if (lm == 0) {
#pragma unroll
        for (int m = 0; m < 4; ++m)
#pragma unroll
            for (int j = 0; j < 4; ++j)
                red[wc][(wr << 6) + (m << 4) + (lq << 2) + j] = rmin[m][j];
    }
    __syncthreads();
    if (tid < 256) {
        float v = fminf(red[0][tid], red[1][tid]);
        atomicMin(out + n0 + tid, __float_as_uint(0.5f * v));
    }
}

extern "C" void kernel_launch(void* const* d_in, const int* in_sizes, int n_in,
                              void* d_out, int out_size, void* d_ws, size_t ws_size,
                              hipStream_t stream) {
    const float* X = (const float*)d_in[0];  // [16384, 256]
    const float* P = (const float*)d_in[1];  // [1024, 256]
    unsigned* out = (unsigned*)d_out;        // [1, 16384] f32 viewed as uint
    int N = in_sizes[0] / D;                 // 16384

    float* ws = (float*)d_ws;
    float* p2 = ws;                  // 1024 f32
    float* hsum = ws + 1024;         // 1024 f32
    float* hp2 = ws + 2048;          // 1024 f32
    short* Gb = (short*)(ws + 4096); // 1024*256 bf16 (512KB)

    p2_kernel<<<NPROTO, 64, 0, stream>>>(P, p2);
    gmat_kernel<<<NPROTO / 4, 512, 0, stream>>>(P, p2, Gb, hsum, hp2);
    init_kernel<<<N / 256, 256, 0, stream>>>(out);
    som2_kernel<<<dim3(N / 256, ISPLIT), 512, 0, stream>>>(X, Gb, hsum, hp2, out);
}

// Round 3
// 55.094 us; speedup vs baseline: 3.1028x; 1.1621x over previous
//
#include <hip/hip_runtime.h>
#include <hip/hip_bf16.h>
#include <math.h>

#define D 256
#define NPROTO 1024
#define WR 13
#define WC 18
#define WJ (WR * WC)

typedef __attribute__((ext_vector_type(8))) short short8;
typedef __attribute__((ext_vector_type(4))) short s16x4;
typedef __attribute__((ext_vector_type(4))) float f32x4;

__device__ __forceinline__ short f2bf(float f) {
    union { __hip_bfloat16 b; short s; } u;
    u.b = __float2bfloat16(f);
    return u.s;
}

__device__ __forceinline__ void gload_lds16(void* lds, const void* g) {
    __builtin_amdgcn_global_load_lds(
        (const __attribute__((address_space(1))) unsigned*)g,
        (__attribute__((address_space(3))) unsigned*)lds, 16, 0, 0);
}

// ---- hex-grid neighborhood H[i,j] on the fly (fp64, matches np ref) ----
__device__ __forceinline__ void proto_pos(int idx, double& x, double& y) {
    int r = idx >> 5, c = idx & 31;
    x = (double)c + 0.5 * (double)(r & 1);
    y = (double)r * 0.86602540378443864676;  // sqrt(3)/2
}

__device__ __forceinline__ float hval(int i, int j) {
    double xi, yi, xj, yj;
    proto_pos(i, xi, yi);
    proto_pos(j, xj, yj);
    double dx0 = xi - xj, dy0 = yi - yj;
    const double W = 32.0;
    const double Hh = 27.712812921102035;  // 32*sqrt(3)/2
    double best = 1e300;
#pragma unroll
    for (int sx = -1; sx <= 1; ++sx) {
        double dx = dx0 + (double)sx * W;
#pragma unroll
        for (int sy = -1; sy <= 1; ++sy) {
            double dy = dy0 + (double)sy * Hh;
            double d2 = dx * dx + dy * dy;
            best = fmin(best, d2);
        }
    }
    return (float)exp(-0.5 * best);
}

// ---- xprep: Xg = bf16(X) PRE-SWIZZLED (byte^((row&7)<<4) within 128B chunks),
//      x2[n] = ||X[n]||^2. 8 rows/block, 32 threads/row, 8 floats/thread. ----
__global__ void __launch_bounds__(256) xprep_kernel(
    const float* __restrict__ X, short* __restrict__ Xg, float* __restrict__ x2) {
    int t = threadIdx.x;
    int row = blockIdx.x * 8 + (t >> 5);
    int g = t & 31;
    const float4* src = reinterpret_cast<const float4*>(X + (size_t)row * D) + g * 2;
    float4 a = src[0], b = src[1];
    float s = a.x * a.x + a.y * a.y + a.z * a.z + a.w * a.w +
              b.x * b.x + b.y * b.y + b.z * b.z + b.w * b.w;
    s += __shfl_xor(s, 1);
    s += __shfl_xor(s, 2);
    s += __shfl_xor(s, 4);
    s += __shfl_xor(s, 8);
    s += __shfl_xor(s, 16);
    if (g == 0) x2[row] = s;
    short8 w;
    w[0] = f2bf(a.x); w[1] = f2bf(a.y); w[2] = f2bf(a.z); w[3] = f2bf(a.w);
    w[4] = f2bf(b.x); w[5] = f2bf(b.y); w[6] = f2bf(b.z); w[7] = f2bf(b.w);
    int sw = ((g * 8) & 63) ^ ((row & 7) << 3);  // short-index swizzle in 64-chunk
    *reinterpret_cast<short8*>(Xg + (size_t)row * D + ((g >> 3) << 6) + sw) = w;
}

// ---- p2[j] = ||P[j]||^2 ----
__global__ void p2_kernel(const float* __restrict__ P, float* __restrict__ p2) {
    int j = blockIdx.x;
    int lane = threadIdx.x;  // 64
    float4 v = reinterpret_cast<const float4*>(P + j * D)[lane];
    float s = v.x * v.x + v.y * v.y + v.z * v.z + v.w * v.w;
#pragma unroll
    for (int off = 32; off >= 1; off >>= 1) s += __shfl_down(s, off);
    if (lane == 0) p2[j] = s;
}

// ---- gmat sparse: H row is local (sigma=1) — only a 13x18 torus window
//      matters (omitted h < 4e-6; energy error << threshold).
//      Block = 4 protos in one map row. Gb stored bf16 PRE-SWIZZLED. ----
__global__ void __launch_bounds__(256) gmat_kernel(
    const float* __restrict__ P, const float* __restrict__ p2,
    short* __restrict__ Gb, float* __restrict__ hsum, float* __restrict__ hp2) {
    __shared__ float ht[4][WJ];
    __shared__ float p2s[WJ];
    __shared__ int jrow[WJ];
    int t = threadIdx.x;
    int i0 = blockIdx.x * 4;
    int r0 = i0 >> 5, c0 = i0 & 31;

    for (int u = t; u < WJ; u += 256) {
        int jr = (r0 + (u / WC) - 6 + 32) & 31;
        int jc = (c0 + (u % WC) - 7 + 32) & 31;
        int j = jr * 32 + jc;
        jrow[u] = j;
        p2s[u] = p2[j];
#pragma unroll
        for (int s = 0; s < 4; ++s) ht[s][u] = hval(i0 + s, j);
    }
    __syncthreads();

    int isub = t >> 6, dq = t & 63;
    f32x4 g = {0.f, 0.f, 0.f, 0.f};
#pragma unroll 4
    for (int u = 0; u < WJ; ++u) {
        f32x4 pv = *reinterpret_cast<const f32x4*>(P + (size_t)jrow[u] * D + dq * 4);
        float h = ht[isub][u];
        g[0] = fmaf(h, pv[0], g[0]);
        g[1] = fmaf(h, pv[1], g[1]);
        g[2] = fmaf(h, pv[2], g[2]);
        g[3] = fmaf(h, pv[3], g[3]);
    }
    int i = i0 + isub;
    s16x4 w = {f2bf(g[0]), f2bf(g[1]), f2bf(g[2]), f2bf(g[3])};
    int sw = ((dq * 4) & 63) ^ ((i & 7) << 3);
    *reinterpret_cast<s16x4*>(Gb + (size_t)i * D + ((dq >> 4) << 6) + sw) = w;

    if (t < 4) {
        float s = 0.f;
        for (int u = 0; u < WJ; ++u) s += ht[t][u];
        hsum[i0 + t] = s;
    } else if (t < 8) {
        float s = 0.f;
        for (int u = 0; u < WJ; ++u) s += ht[t - 4][u] * p2s[u];
        hp2[i0 + t - 4] = s;
    }
}

// ---- init out to +inf ----
__global__ void init_kernel(unsigned* __restrict__ out) {
    out[blockIdx.x * 256 + threadIdx.x] = 0x7f800000u;  // +inf
}

// ---- som3: 128n x 128i tile, 256 thr (4 waves 2x2, wave tile 64x64),
//      BK=64, dbuf 64KB LDS (2 blocks/CU), all staging via global_load_lds
//      from pre-swizzled bf16 operands. acc = 64 VGPRs. ----
__global__ void __launch_bounds__(256, 2) som3_kernel(
    const short* __restrict__ Xg, const short* __restrict__ Gb,
    const float* __restrict__ x2, const float* __restrict__ hsum,
    const float* __restrict__ hp2, unsigned* __restrict__ out) {
    __shared__ __align__(16) short Xs[2][128 * 64];  // 16KB each
    __shared__ __align__(16) short Gs[2][128 * 64];
    __shared__ float red[2][128];

    const int t = threadIdx.x;
    const int lane = t & 63;
    const int wid = t >> 6;
    const int wr = wid >> 1;  // n half (64 rows)
    const int wc = wid & 1;   // i half (64 cols)
    const int lm = lane & 15;
    const int lq = lane >> 4;
    const int n0 = blockIdx.x * 128;
    const int ib = blockIdx.y * 128;

    f32x4 acc[4][4];
#pragma unroll
    for (int m = 0; m < 4; ++m)
#pragma unroll
        for (int n = 0; n < 4; ++n) acc[m][n] = (f32x4){0.f, 0.f, 0.f, 0.f};

    auto stage = [&](int nb, int kt) {
#pragma unroll
        for (int q = 0; q < 4; ++q) {
            int row = q * 32 + (t >> 3);
            gload_lds16((char*)(&Xs[nb][0]) + q * 4096 + t * 16,
                        Xg + (size_t)(n0 + row) * D + kt * 64 + (t & 7) * 8);
        }
#pragma unroll
        for (int q = 0; q < 4; ++q) {
            int row = q * 32 + (t >> 3);
            gload_lds16((char*)(&Gs[nb][0]) + q * 4096 + t * 16,
                        Gb + (size_t)(ib + row) * D + kt * 64 + (t & 7) * 8);
        }
    };

    auto compute = [&](int cur) {
#pragma unroll
        for (int kk = 0; kk < 2; ++kk) {
            const int off = (kk * 32 + lq * 8) ^ ((lm & 7) << 3);  // short idx
            short8 a[4], b[4];
#pragma unroll
            for (int m = 0; m < 4; ++m)
                a[m] = *reinterpret_cast<const short8*>(
                    &Xs[cur][(wr * 64 + m * 16 + lm) * 64 + off]);
#pragma unroll
            for (int n = 0; n < 4; ++n)
                b[n] = *reinterpret_cast<const short8*>(
                    &Gs[cur][(wc * 64 + n * 16 + lm) * 64 + off]);
#pragma unroll
            for (int m = 0; m < 4; ++m)
#pragma unroll
                for (int n = 0; n < 4; ++n)
                    acc[m][n] = __builtin_amdgcn_mfma_f32_16x16x32_bf16(a[m], b[n], acc[m][n], 0, 0, 0);
        }
    };

    stage(0, 0);
#pragma unroll
    for (int kt = 0; kt < 4; ++kt) {
        __syncthreads();
        if (kt < 3) stage((kt + 1) & 1, kt + 1);
        compute(kt & 1);
    }

    // ---- epilogue: e = hsum*x2 + hp2 - 2*acc, running min over i ----
    float x2v[4][4];
#pragma unroll
    for (int m = 0; m < 4; ++m)
#pragma unroll
        for (int j = 0; j < 4; ++j)
            x2v[m][j] = x2[n0 + wr * 64 + m * 16 + lq * 4 + j];

    float rmin[4][4];
#pragma unroll
    for (int m = 0; m < 4; ++m)
#pragma unroll
        for (int j = 0; j < 4; ++j) rmin[m][j] = 3.4e38f;

#pragma unroll
    for (int ni = 0; ni < 4; ++ni) {
        int ig = ib + wc * 64 + ni * 16 + lm;
        float hs = hsum[ig];
        float hq = hp2[ig];
#pragma unroll
        for (int m = 0; m < 4; ++m)
#pragma unroll
            for (int j = 0; j < 4; ++j) {
                float e = fmaf(hs, x2v[m][j], hq) - 2.0f * acc[m][ni][j];
                rmin[m][j] = fminf(rmin[m][j], e);
            }
    }

#pragma unroll
    for (int m = 0; m < 4; ++m)
#pragma unroll
        for (int j = 0; j < 4; ++j) {
            float v = rmin[m][j];
            v = fminf(v, __shfl_xor(v, 1));
            v = fminf(v, __shfl_xor(v, 2));
            v = fminf(v, __shfl_xor(v, 4));
            v = fminf(v, __shfl_xor(v, 8));
            rmin[m][j] = v;
        }
    if (lm == 0) {
#pragma unroll
        for (int m = 0; m < 4; ++m)
#pragma unroll
            for (int j = 0; j < 4; ++j)
                red[wc][wr * 64 + m * 16 + lq * 4 + j] = rmin[m][j];
    }
    __syncthreads();
    if (t < 128) {
        float v = fminf(red[0][t], red[1][t]);
        atomicMin(out + n0 + t, __float_as_uint(0.5f * v));
    }
}

extern "C" void kernel_launch(void* const* d_in, const int* in_sizes, int n_in,
                              void* d_out, int out_size, void* d_ws, size_t ws_size,
                              hipStream_t stream) {
    const float* X = (const float*)d_in[0];  // [16384, 256]
    const float* P = (const float*)d_in[1];  // [1024, 256]
    unsigned* out = (unsigned*)d_out;        // [1, 16384] f32 as uint
    int N = in_sizes[0] / D;                 // 16384

    float* ws = (float*)d_ws;
    float* p2 = ws;                      // 1024 f32
    float* hsum = ws + 1024;             // 1024 f32
    float* hp2 = ws + 2048;              // 1024 f32
    float* x2 = ws + 4096;               // 16384 f32
    short* Gb = (short*)(ws + 32768);    // 1024*256 bf16 (512KB) @ 128KB
    short* Xg = (short*)(ws + 262144);   // 16384*256 bf16 (8.4MB) @ 1MB

    xprep_kernel<<<N / 8, 256, 0, stream>>>(X, Xg, x2);
    p2_kernel<<<NPROTO, 64, 0, stream>>>(P, p2);
    gmat_kernel<<<NPROTO / 4, 256, 0, stream>>>(P, p2, Gb, hsum, hp2);
    init_kernel<<<N / 256, 256, 0, stream>>>(out);
    som3_kernel<<<dim3(N / 128, NPROTO / 128), 256, 0, stream>>>(Xg, Gb, x2, hsum, hp2, out);
}

// Round 4
// 46.744 us; speedup vs baseline: 3.6571x; 1.1786x over previous
//
#include <hip/hip_runtime.h>
#include <hip/hip_bf16.h>
#include <math.h>

#define D 256
#define NPROTO 1024
#define WR 13
#define WC 18
#define WJ (WR * WC)
#define GMAT_BLOCKS (NPROTO / 4)   // 256
#define XPREP_BLOCKS (16384 / 8)   // 2048

typedef __attribute__((ext_vector_type(8))) short short8;
typedef __attribute__((ext_vector_type(4))) short s16x4;
typedef __attribute__((ext_vector_type(4))) float f32x4;

__device__ __forceinline__ short f2bf(float f) {
    union { __hip_bfloat16 b; short s; } u;
    u.b = __float2bfloat16(f);
    return u.s;
}

__device__ __forceinline__ void gload_lds16(void* lds, const void* g) {
    __builtin_amdgcn_global_load_lds(
        (const __attribute__((address_space(1))) unsigned*)g,
        (__attribute__((address_space(3))) unsigned*)lds, 16, 0, 0);
}

// ---- hex-grid neighborhood H[i,j] on the fly (fp64, matches np ref) ----
__device__ __forceinline__ void proto_pos(int idx, double& x, double& y) {
    int r = idx >> 5, c = idx & 31;
    x = (double)c + 0.5 * (double)(r & 1);
    y = (double)r * 0.86602540378443864676;  // sqrt(3)/2
}

__device__ __forceinline__ float hval(int i, int j) {
    double xi, yi, xj, yj;
    proto_pos(i, xi, yi);
    proto_pos(j, xj, yj);
    double dx0 = xi - xj, dy0 = yi - yj;
    const double W = 32.0;
    const double Hh = 27.712812921102035;  // 32*sqrt(3)/2
    double best = 1e300;
#pragma unroll
    for (int sx = -1; sx <= 1; ++sx) {
        double dx = dx0 + (double)sx * W;
#pragma unroll
        for (int sy = -1; sy <= 1; ++sy) {
            double dy = dy0 + (double)sy * Hh;
            double d2 = dx * dx + dy * dy;
            best = fmin(best, d2);
        }
    }
    return (float)exp(-0.5 * best);
}

// ---- prep: role-split single kernel.
//  blocks [0, 256):      gmat — Gb = bf16(H@P) pre-swizzled, hsum, hp2
//                        (sparse 13x18 torus window; p2 folded in-loop)
//  blocks [256, 2304):   xprep — Xg = bf16(X) pre-swizzled, x2, out=+inf ----
__global__ void __launch_bounds__(256) prep_kernel(
    const float* __restrict__ X, const float* __restrict__ P,
    short* __restrict__ Xg, short* __restrict__ Gb,
    float* __restrict__ x2, float* __restrict__ hsum, float* __restrict__ hp2,
    unsigned* __restrict__ out) {
    int t = threadIdx.x;
    int bx = blockIdx.x;

    if (bx >= GMAT_BLOCKS) {
        // ---------------- xprep ----------------
        int row = (bx - GMAT_BLOCKS) * 8 + (t >> 5);
        int g = t & 31;
        const float4* src = reinterpret_cast<const float4*>(X + (size_t)row * D) + g * 2;
        float4 a = src[0], b = src[1];
        float s = a.x * a.x + a.y * a.y + a.z * a.z + a.w * a.w +
                  b.x * b.x + b.y * b.y + b.z * b.z + b.w * b.w;
        s += __shfl_xor(s, 1);
        s += __shfl_xor(s, 2);
        s += __shfl_xor(s, 4);
        s += __shfl_xor(s, 8);
        s += __shfl_xor(s, 16);
        if (g == 0) x2[row] = s;
        short8 w;
        w[0] = f2bf(a.x); w[1] = f2bf(a.y); w[2] = f2bf(a.z); w[3] = f2bf(a.w);
        w[4] = f2bf(b.x); w[5] = f2bf(b.y); w[6] = f2bf(b.z); w[7] = f2bf(b.w);
        int sw = ((g * 8) & 63) ^ ((row & 7) << 3);  // short-index swizzle in 64-chunk
        *reinterpret_cast<short8*>(Xg + (size_t)row * D + ((g >> 3) << 6) + sw) = w;
        if (t < 8) out[(bx - GMAT_BLOCKS) * 8 + t] = 0x7f800000u;  // +inf
        return;
    }

    // ---------------- gmat ----------------
    __shared__ float ht[4][WJ];
    __shared__ int jrow[WJ];
    int i0 = bx * 4;
    int r0 = i0 >> 5, c0 = i0 & 31;

    for (int u = t; u < WJ; u += 256) {
        int jr = (r0 + (u / WC) - 6 + 32) & 31;
        int jc = (c0 + (u % WC) - 7 + 32) & 31;
        int j = jr * 32 + jc;
        jrow[u] = j;
#pragma unroll
        for (int s = 0; s < 4; ++s) ht[s][u] = hval(i0 + s, j);
    }
    __syncthreads();

    int isub = t >> 6, dq = t & 63;   // one wave per proto
    f32x4 g = {0.f, 0.f, 0.f, 0.f};
    float qacc = 0.f;
#pragma unroll 4
    for (int u = 0; u < WJ; ++u) {
        f32x4 pv = *reinterpret_cast<const f32x4*>(P + (size_t)jrow[u] * D + dq * 4);
        float h = ht[isub][u];
        g[0] = fmaf(h, pv[0], g[0]);
        g[1] = fmaf(h, pv[1], g[1]);
        g[2] = fmaf(h, pv[2], g[2]);
        g[3] = fmaf(h, pv[3], g[3]);
        qacc = fmaf(h, pv[0] * pv[0] + pv[1] * pv[1] + pv[2] * pv[2] + pv[3] * pv[3], qacc);
    }
    int i = i0 + isub;
    s16x4 w = {f2bf(g[0]), f2bf(g[1]), f2bf(g[2]), f2bf(g[3])};
    int sw = ((dq * 4) & 63) ^ ((i & 7) << 3);
    *reinterpret_cast<s16x4*>(Gb + (size_t)i * D + ((dq >> 4) << 6) + sw) = w;

    // hsum (lane-strided over ht) and hp2 (qacc) wave reductions
    float hsacc = 0.f;
    for (int u = dq; u < WJ; u += 64) hsacc += ht[isub][u];
#pragma unroll
    for (int off = 1; off < 64; off <<= 1) {
        qacc += __shfl_xor(qacc, off);
        hsacc += __shfl_xor(hsacc, off);
    }
    if (dq == 0) {
        hp2[i] = qacc;
        hsum[i] = hsacc;
    }
}

// ---- som4: block tile 128n x 256i (two 128-i subtiles), grid 128x4 = 512
//      blocks (exactly 2/CU, one round). 8 compute phases/block; X staged
//      once per kt, reused by both subtiles. 256 thr (4 waves 2x2). ----
__global__ void __launch_bounds__(256, 2) som4_kernel(
    const short* __restrict__ Xg, const short* __restrict__ Gb,
    const float* __restrict__ x2, const float* __restrict__ hsum,
    const float* __restrict__ hp2, unsigned* __restrict__ out) {
    __shared__ __align__(16) short Xs[2][128 * 64];  // 16KB each
    __shared__ __align__(16) short Gs[2][128 * 64];
    __shared__ float red[2][128];

    const int t = threadIdx.x;
    const int lane = t & 63;
    const int wid = t >> 6;
    const int wr = wid >> 1;  // n half (64 rows)
    const int wc = wid & 1;   // i half (64 cols within subtile)
    const int lm = lane & 15;
    const int lq = lane >> 4;
    const int n0 = blockIdx.x * 128;
    const int ib0 = blockIdx.y * 256;

    f32x4 acc[2][4][4];
#pragma unroll
    for (int it = 0; it < 2; ++it)
#pragma unroll
        for (int m = 0; m < 4; ++m)
#pragma unroll
            for (int n = 0; n < 4; ++n) acc[it][m][n] = (f32x4){0.f, 0.f, 0.f, 0.f};

    auto stage_X = [&](int xb, int kt) {
#pragma unroll
        for (int q = 0; q < 4; ++q) {
            int row = q * 32 + (t >> 3);
            gload_lds16((char*)(&Xs[xb][0]) + q * 4096 + t * 16,
                        Xg + (size_t)(n0 + row) * D + kt * 64 + (t & 7) * 8);
        }
    };
    auto stage_G = [&](int gb, int kt, int it) {
#pragma unroll
        for (int q = 0; q < 4; ++q) {
            int row = q * 32 + (t >> 3);
            gload_lds16((char*)(&Gs[gb][0]) + q * 4096 + t * 16,
                        Gb + (size_t)(ib0 + it * 128 + row) * D + kt * 64 + (t & 7) * 8);
        }
    };

    auto compute = [&](int xb, int gb, int it) {
#pragma unroll
        for (int kk = 0; kk < 2; ++kk) {
            const int off = (kk * 32 + lq * 8) ^ ((lm & 7) << 3);  // short idx
            short8 a[4], b[4];
#pragma unroll
            for (int m = 0; m < 4; ++m)
                a[m] = *reinterpret_cast<const short8*>(
                    &Xs[xb][(wr * 64 + m * 16 + lm) * 64 + off]);
#pragma unroll
            for (int n = 0; n < 4; ++n)
                b[n] = *reinterpret_cast<const short8*>(
                    &Gs[gb][(wc * 64 + n * 16 + lm) * 64 + off]);
#pragma unroll
            for (int m = 0; m < 4; ++m)
#pragma unroll
                for (int n = 0; n < 4; ++n)
                    acc[it][m][n] = __builtin_amdgcn_mfma_f32_16x16x32_bf16(a[m], b[n], acc[it][m][n], 0, 0, 0);
        }
    };

    stage_X(0, 0);
    stage_G(0, 0, 0);
    // phases p = kt*2 + it; xbuf = kt&1, gbuf = p&1
#pragma unroll
    for (int p = 0; p < 8; ++p) {
        __syncthreads();
        if (p < 7) {
            const int pn = p + 1, ktn = pn >> 1, itn = pn & 1;
            if (itn == 0) stage_X(ktn & 1, ktn);
            stage_G(pn & 1, ktn, itn);
        }
        compute((p >> 1) & 1, p & 1, p & 1);
    }

    // ---- epilogue: e = hsum*x2 + hp2 - 2*acc; min over all 256 i ----
    float x2v[4][4];
#pragma unroll
    for (int m = 0; m < 4; ++m)
#pragma unroll
        for (int j = 0; j < 4; ++j)
            x2v[m][j] = x2[n0 + wr * 64 + m * 16 + lq * 4 + j];

    float rmin[4][4];
#pragma unroll
    for (int m = 0; m < 4; ++m)
#pragma unroll
        for (int j = 0; j < 4; ++j) rmin[m][j] = 3.4e38f;

#pragma unroll
    for (int it = 0; it < 2; ++it)
#pragma unroll
        for (int ni = 0; ni < 4; ++ni) {
            int ig = ib0 + it * 128 + wc * 64 + ni * 16 + lm;
            float hs = hsum[ig];
            float hq = hp2[ig];
#pragma unroll
            for (int m = 0; m < 4; ++m)
#pragma unroll
                for (int j = 0; j < 4; ++j) {
                    float e = fmaf(hs, x2v[m][j], hq) - 2.0f * acc[it][m][ni][j];
                    rmin[m][j] = fminf(rmin[m][j], e);
                }
        }

#pragma unroll
    for (int m = 0; m < 4; ++m)
#pragma unroll
        for (int j = 0; j < 4; ++j) {
            float v = rmin[m][j];
            v = fminf(v, __shfl_xor(v, 1));
            v = fminf(v, __shfl_xor(v, 2));
            v = fminf(v, __shfl_xor(v, 4));
            v = fminf(v, __shfl_xor(v, 8));
            rmin[m][j] = v;
        }
    if (lm == 0) {
#pragma unroll
        for (int m = 0; m < 4; ++m)
#pragma unroll
            for (int j = 0; j < 4; ++j)
                red[wc][wr * 64 + m * 16 + lq * 4 + j] = rmin[m][j];
    }
    __syncthreads();
    if (t < 128) {
        float v = fminf(red[0][t], red[1][t]);
        atomicMin(out + n0 + t, __float_as_uint(0.5f * v));
    }
}

extern "C" void kernel_launch(void* const* d_in, const int* in_sizes, int n_in,
                              void* d_out, int out_size, void* d_ws, size_t ws_size,
                              hipStream_t stream) {
    const float* X = (const float*)d_in[0];  // [16384, 256]
    const float* P = (const float*)d_in[1];  // [1024, 256]
    unsigned* out = (unsigned*)d_out;        // [1, 16384] f32 as uint
    int N = in_sizes[0] / D;                 // 16384

    float* ws = (float*)d_ws;
    float* hsum = ws + 1024;             // 1024 f32
    float* hp2 = ws + 2048;              // 1024 f32
    float* x2 = ws + 4096;               // 16384 f32
    short* Gb = (short*)(ws + 32768);    // 1024*256 bf16 (512KB) @ 128KB
    short* Xg = (short*)(ws + 262144);   // 16384*256 bf16 (8.4MB) @ 1MB

    prep_kernel<<<GMAT_BLOCKS + XPREP_BLOCKS, 256, 0, stream>>>(
        X, P, Xg, Gb, x2, hsum, hp2, out);
    som4_kernel<<<dim3(N / 128, NPROTO / 256), 256, 0, stream>>>(
        Xg, Gb, x2, hsum, hp2, out);
}

// Round 5
// 31.972 us; speedup vs baseline: 5.3468x; 1.4621x over previous
//
#include <hip/hip_runtime.h>
#include <hip/hip_bf16.h>
#include <math.h>

#define D 256
#define NPROTO 1024
#define WR 13
#define WC 18
#define WJ (WR * WC)
#define JSUB 59                    // ceil(WJ/4)
#define GMAT_BLOCKS (NPROTO / 4)   // 256
#define XPREP_BLOCKS (16384 / 8)   // 2048

#define WAITVM(N) asm volatile("s_waitcnt vmcnt(" #N ")" ::: "memory")

typedef __attribute__((ext_vector_type(8))) short short8;
typedef __attribute__((ext_vector_type(4))) short s16x4;
typedef __attribute__((ext_vector_type(4))) float f32x4;

__device__ __forceinline__ short f2bf(float f) {
    union { __hip_bfloat16 b; short s; } u;
    u.b = __float2bfloat16(f);
    return u.s;
}

__device__ __forceinline__ void gload_lds16(void* lds, const void* g) {
    __builtin_amdgcn_global_load_lds(
        (const __attribute__((address_space(1))) unsigned*)g,
        (__attribute__((address_space(3))) unsigned*)lds, 16, 0, 0);
}

// ---- hex-grid neighborhood H[i,j] on the fly (fp64, matches np ref) ----
__device__ __forceinline__ void proto_pos(int idx, double& x, double& y) {
    int r = idx >> 5, c = idx & 31;
    x = (double)c + 0.5 * (double)(r & 1);
    y = (double)r * 0.86602540378443864676;  // sqrt(3)/2
}

__device__ __forceinline__ float hval(int i, int j) {
    double xi, yi, xj, yj;
    proto_pos(i, xi, yi);
    proto_pos(j, xj, yj);
    double dx0 = xi - xj, dy0 = yi - yj;
    const double W = 32.0;
    const double Hh = 27.712812921102035;  // 32*sqrt(3)/2
    double best = 1e300;
#pragma unroll
    for (int sx = -1; sx <= 1; ++sx) {
        double dx = dx0 + (double)sx * W;
#pragma unroll
        for (int sy = -1; sy <= 1; ++sy) {
            double dy = dy0 + (double)sy * Hh;
            double d2 = dx * dx + dy * dy;
            best = fmin(best, d2);
        }
    }
    return (float)exp(-0.5 * best);
}

// ---- prep: role-split single kernel.
//  blocks [0, 256):      gmat — Gb = bf16(H@P) pre-swizzled, hsum, hp2
//                        (sparse 13x18 torus window; 4-wave j-split: each wave
//                        covers ~59 j's for ALL 4 protos -> P read once/block)
//  blocks [256, 2304):   xprep — Xg = bf16(X) pre-swizzled, x2, out=+inf ----
__global__ void __launch_bounds__(256) prep_kernel(
    const float* __restrict__ X, const float* __restrict__ P,
    short* __restrict__ Xg, short* __restrict__ Gb,
    float* __restrict__ x2, float* __restrict__ hsum, float* __restrict__ hp2,
    unsigned* __restrict__ out) {
    int t = threadIdx.x;
    int bx = blockIdx.x;

    if (bx >= GMAT_BLOCKS) {
        // ---------------- xprep ----------------
        int row = (bx - GMAT_BLOCKS) * 8 + (t >> 5);
        int g = t & 31;
        const float4* src = reinterpret_cast<const float4*>(X + (size_t)row * D) + g * 2;
        float4 a = src[0], b = src[1];
        float s = a.x * a.x + a.y * a.y + a.z * a.z + a.w * a.w +
                  b.x * b.x + b.y * b.y + b.z * b.z + b.w * b.w;
        s += __shfl_xor(s, 1);
        s += __shfl_xor(s, 2);
        s += __shfl_xor(s, 4);
        s += __shfl_xor(s, 8);
        s += __shfl_xor(s, 16);
        if (g == 0) x2[row] = s;
        short8 w;
        w[0] = f2bf(a.x); w[1] = f2bf(a.y); w[2] = f2bf(a.z); w[3] = f2bf(a.w);
        w[4] = f2bf(b.x); w[5] = f2bf(b.y); w[6] = f2bf(b.z); w[7] = f2bf(b.w);
        int sw = ((g * 8) & 63) ^ ((row & 7) << 3);  // short-index swizzle in 64-chunk
        *reinterpret_cast<short8*>(Xg + (size_t)row * D + ((g >> 3) << 6) + sw) = w;
        if (t < 8) out[(bx - GMAT_BLOCKS) * 8 + t] = 0x7f800000u;  // +inf
        return;
    }

    // ---------------- gmat ----------------
    __shared__ float ht[4][WJ];
    __shared__ int jrow[WJ];
    __shared__ __align__(16) float gpart[4][4][256];  // wave x proto x d, 16KB
    __shared__ float hqred[4][4];                     // wave x proto
    __shared__ float hsred[4][4];
    int i0 = bx * 4;
    int r0 = i0 >> 5, c0 = i0 & 31;

    for (int u = t; u < WJ; u += 256) {
        int jr = (r0 + (u / WC) - 6 + 32) & 31;
        int jc = (c0 + (u % WC) - 7 + 32) & 31;
        int j = jr * 32 + jc;
        jrow[u] = j;
#pragma unroll
        for (int s = 0; s < 4; ++s) ht[s][u] = hval(i0 + s, j);
    }
    __syncthreads();

    int w = t >> 6, lane = t & 63;
    int j0 = w * JSUB;
    int j1 = (j0 + JSUB < WJ) ? j0 + JSUB : WJ;
    f32x4 g[4] = {{0.f, 0.f, 0.f, 0.f}, {0.f, 0.f, 0.f, 0.f},
                  {0.f, 0.f, 0.f, 0.f}, {0.f, 0.f, 0.f, 0.f}};
    float hqp[4] = {0.f, 0.f, 0.f, 0.f};
    float hsp[4] = {0.f, 0.f, 0.f, 0.f};
    for (int u = j0; u < j1; ++u) {
        f32x4 pv = *reinterpret_cast<const f32x4*>(P + (size_t)jrow[u] * D + lane * 4);
        float q = pv[0] * pv[0] + pv[1] * pv[1] + pv[2] * pv[2] + pv[3] * pv[3];
#pragma unroll
        for (int s = 0; s < 4; ++s) {
            float h = ht[s][u];
            g[s][0] = fmaf(h, pv[0], g[s][0]);
            g[s][1] = fmaf(h, pv[1], g[s][1]);
            g[s][2] = fmaf(h, pv[2], g[s][2]);
            g[s][3] = fmaf(h, pv[3], g[s][3]);
            hqp[s] = fmaf(h, q, hqp[s]);
            hsp[s] += h;  // lane-uniform
        }
    }
#pragma unroll
    for (int s = 0; s < 4; ++s)
        *reinterpret_cast<f32x4*>(&gpart[w][s][lane * 4]) = g[s];
    // reduce hqp across 64 lanes
#pragma unroll
    for (int s = 0; s < 4; ++s) {
#pragma unroll
        for (int off = 1; off < 64; off <<= 1) hqp[s] += __shfl_xor(hqp[s], off);
    }
    if (lane == 0) {
#pragma unroll
        for (int s = 0; s < 4; ++s) { hqred[w][s] = hqp[s]; hsred[w][s] = hsp[s]; }
    }
    __syncthreads();

    // final: G row per proto (t>>6 = proto, lane covers d)
    {
        int s = t >> 6;
        f32x4 gs = *reinterpret_cast<const f32x4*>(&gpart[0][s][lane * 4]);
#pragma unroll
        for (int ww = 1; ww < 4; ++ww) {
            f32x4 gp = *reinterpret_cast<const f32x4*>(&gpart[ww][s][lane * 4]);
            gs[0] += gp[0]; gs[1] += gp[1]; gs[2] += gp[2]; gs[3] += gp[3];
        }
        int i = i0 + s;
        s16x4 wv = {f2bf(gs[0]), f2bf(gs[1]), f2bf(gs[2]), f2bf(gs[3])};
        int sw = ((lane * 4) & 63) ^ ((i & 7) << 3);
        *reinterpret_cast<s16x4*>(Gb + (size_t)i * D + ((lane >> 4) << 6) + sw) = wv;
    }
    if (t < 4) {
        hsum[i0 + t] = hsred[0][t] + hsred[1][t] + hsred[2][t] + hsred[3][t];
    } else if (t < 8) {
        int s = t - 4;
        hp2[i0 + s] = hqred[0][s] + hqred[1][s] + hqred[2][s] + hqred[3][s];
    }
}

// ---- som5: block tile 128n x 256i, 512 blocks (2/CU), 8 phases with
//      COUNTED vmcnt (T3+T4): stage(p+1) stays in flight across compute(p).
//      Per phase: issue -> vmcnt(4/8) -> bar -> ds_read+MFMA (setprio) -> bar.
__global__ void __launch_bounds__(256, 2) som5_kernel(
    const short* __restrict__ Xg, const short* __restrict__ Gb,
    const float* __restrict__ x2, const float* __restrict__ hsum,
    const float* __restrict__ hp2, unsigned* __restrict__ out) {
    __shared__ __align__(16) short Xs[2][128 * 64];  // 16KB each
    __shared__ __align__(16) short Gs[2][128 * 64];
    __shared__ float red[2][128];

    const int t = threadIdx.x;
    const int lane = t & 63;
    const int wid = t >> 6;
    const int wr = wid >> 1;  // n half (64 rows)
    const int wc = wid & 1;   // i half (64 cols within subtile)
    const int lm = lane & 15;
    const int lq = lane >> 4;
    const int n0 = blockIdx.x * 128;
    const int ib0 = blockIdx.y * 256;

    f32x4 acc[2][4][4];
#pragma unroll
    for (int it = 0; it < 2; ++it)
#pragma unroll
        for (int m = 0; m < 4; ++m)
#pragma unroll
            for (int n = 0; n < 4; ++n) acc[it][m][n] = (f32x4){0.f, 0.f, 0.f, 0.f};

    auto stage_X = [&](int xb, int kt) {
#pragma unroll
        for (int q = 0; q < 4; ++q) {
            int row = q * 32 + (t >> 3);
            gload_lds16((char*)(&Xs[xb][0]) + q * 4096 + t * 16,
                        Xg + (size_t)(n0 + row) * D + kt * 64 + (t & 7) * 8);
        }
    };
    auto stage_G = [&](int gb, int kt, int it) {
#pragma unroll
        for (int q = 0; q < 4; ++q) {
            int row = q * 32 + (t >> 3);
            gload_lds16((char*)(&Gs[gb][0]) + q * 4096 + t * 16,
                        Gb + (size_t)(ib0 + it * 128 + row) * D + kt * 64 + (t & 7) * 8);
        }
    };

    auto compute = [&](int xb, int gb, int it) {
#pragma unroll
        for (int kk = 0; kk < 2; ++kk) {
            const int off = (kk * 32 + lq * 8) ^ ((lm & 7) << 3);  // short idx
            short8 a[4], b[4];
#pragma unroll
            for (int m = 0; m < 4; ++m)
                a[m] = *reinterpret_cast<const short8*>(
                    &Xs[xb][(wr * 64 + m * 16 + lm) * 64 + off]);
#pragma unroll
            for (int n = 0; n < 4; ++n)
                b[n] = *reinterpret_cast<const short8*>(
                    &Gs[gb][(wc * 64 + n * 16 + lm) * 64 + off]);
            __builtin_amdgcn_s_setprio(1);
#pragma unroll
            for (int m = 0; m < 4; ++m)
#pragma unroll
                for (int n = 0; n < 4; ++n)
                    acc[it][m][n] = __builtin_amdgcn_mfma_f32_16x16x32_bf16(a[m], b[n], acc[it][m][n], 0, 0, 0);
            __builtin_amdgcn_s_setprio(0);
        }
    };

    // prologue: stage phase 0 (8 VMEM instrs outstanding)
    stage_G(0, 0, 0);
    stage_X(0, 0);

    // phases p = kt*2 + it. B: issue stage(p+1); C: counted vmcnt; D: barrier;
    // A/E: ds_read + MFMA; F: barrier. Buffer rotation: X by kt&1, G by p&1.
#pragma unroll
    for (int p = 0; p < 8; ++p) {
        if (p < 7) {
            const int pn = p + 1, ktn = pn >> 1, itn = pn & 1;
            if (itn == 0) stage_X(ktn & 1, ktn);   // one phase ahead of use
            stage_G(pn & 1, ktn, itn);
        }
        // counted wait: retire everything issued BEFORE this phase's B.
        if (p == 7) { WAITVM(0); }
        else if (p & 1) { WAITVM(8); }   // odd p: B had G+X = 8 instrs
        else { WAITVM(4); }              // even p: B had G = 4 instrs
        __builtin_amdgcn_sched_barrier(0);
        __builtin_amdgcn_s_barrier();
        compute((p >> 1) & 1, p & 1, p & 1);
        __builtin_amdgcn_s_barrier();
    }

    // ---- epilogue: e = hsum*x2 + hp2 - 2*acc; min over all 256 i ----
    float x2v[4][4];
#pragma unroll
    for (int m = 0; m < 4; ++m)
#pragma unroll
        for (int j = 0; j < 4; ++j)
            x2v[m][j] = x2[n0 + wr * 64 + m * 16 + lq * 4 + j];

    float rmin[4][4];
#pragma unroll
    for (int m = 0; m < 4; ++m)
#pragma unroll
        for (int j = 0; j < 4; ++j) rmin[m][j] = 3.4e38f;

#pragma unroll
    for (int it = 0; it < 2; ++it)
#pragma unroll
        for (int ni = 0; ni < 4; ++ni) {
            int ig = ib0 + it * 128 + wc * 64 + ni * 16 + lm;
            float hs = hsum[ig];
            float hq = hp2[ig];
#pragma unroll
            for (int m = 0; m < 4; ++m)
#pragma unroll
                for (int j = 0; j < 4; ++j) {
                    float e = fmaf(hs, x2v[m][j], hq) - 2.0f * acc[it][m][ni][j];
                    rmin[m][j] = fminf(rmin[m][j], e);
                }
        }

#pragma unroll
    for (int m = 0; m < 4; ++m)
#pragma unroll
        for (int j = 0; j < 4; ++j) {
            float v = rmin[m][j];
            v = fminf(v, __shfl_xor(v, 1));
            v = fminf(v, __shfl_xor(v, 2));
            v = fminf(v, __shfl_xor(v, 4));
            v = fminf(v, __shfl_xor(v, 8));
            rmin[m][j] = v;
        }
    if (lm == 0) {
#pragma unroll
        for (int m = 0; m < 4; ++m)
#pragma unroll
            for (int j = 0; j < 4; ++j)
                red[wc][wr * 64 + m * 16 + lq * 4 + j] = rmin[m][j];
    }
    __syncthreads();
    if (t < 128) {
        float v = fminf(red[0][t], red[1][t]);
        atomicMin(out + n0 + t, __float_as_uint(0.5f * v));
    }
}

extern "C" void kernel_launch(void* const* d_in, const int* in_sizes, int n_in,
                              void* d_out, int out_size, void* d_ws, size_t ws_size,
                              hipStream_t stream) {
    const float* X = (const float*)d_in[0];  // [16384, 256]
    const float* P = (const float*)d_in[1];  // [1024, 256]
    unsigned* out = (unsigned*)d_out;        // [1, 16384] f32 as uint
    int N = in_sizes[0] / D;                 // 16384

    float* ws = (float*)d_ws;
    float* hsum = ws + 1024;             // 1024 f32
    float* hp2 = ws + 2048;              // 1024 f32
    float* x2 = ws + 4096;               // 16384 f32
    short* Gb = (short*)(ws + 32768);    // 1024*256 bf16 (512KB) @ 128KB
    short* Xg = (short*)(ws + 262144);   // 16384*256 bf16 (8.4MB) @ 1MB

    prep_kernel<<<GMAT_BLOCKS + XPREP_BLOCKS, 256, 0, stream>>>(
        X, P, Xg, Gb, x2, hsum, hp2, out);
    som5_kernel<<<dim3(N / 128, NPROTO / 256), 256, 0, stream>>>(
        Xg, Gb, x2, hsum, hp2, out);
}